// Round 7
// baseline (122.346 us; speedup 1.0000x reference)
//
#include <hip/hip_runtime.h>

// Modulated deformable conv2d, fp32 in/out, bf16 MFMA core.
// B=4, C=64, H=W=128, O=64, K=3x3, stride=1, pad=1, dil=1, og=1, groups=1.
//
// Round 12: r11's LDS-window fix worked (main kernel now < 43 us fill floor,
// total 121.5 -> 100.1). Remaining serial fat: the NHWC prep kernel (~10 us +
// launch gap) exists only to feed the staging phase. Merge it: each block
// stages its 16x16-px window DIRECTLY from NCHW fp32 x (clamped cols and LDS
// swizzle offsets are row-invariant -> ~16 instr/row/thread), and the rare
// out-of-window fallback reads NCHW fp32 with the same fp32->bf16 cast.
// LDS layout / swizzle / main loop / wf / epilogue identical to r11 (passed,
// absmax 0.0156). wfrag stays as a tiny standalone launch (72 KB).
// Fragment layouts (m89/m120-verified): A[m=lane&15][k=quad*8+j],
// B[k=quad*8+j][n=lane&15], D[row=quad*4+reg][col=lane&15].

#define BB 4
#define CC 64
#define HH 128
#define WW 128
#define OO 64
#define KHW 3
#define KK 9
#define HW (HH * WW)

typedef __bf16 bf16_t;
typedef bf16_t bf16x8 __attribute__((ext_vector_type(8)));
typedef float f32x4 __attribute__((ext_vector_type(4)));

// ---- weight [O][C][3][3] fp32 -> B-fragment order bf16 ----
// wf element index: ((tap*2+q)*4+nt)*64*8 + lane*8 + j
//   holds W[o = nt*16 + (lane&15)][c = q*32 + (lane>>4)*8 + j][tap]
__global__ void wfrag_kernel(const float* __restrict__ w,
                             bf16_t* __restrict__ wf) {
    int i = blockIdx.x * blockDim.x + threadIdx.x;
    if (i >= OO * CC * KK) return;
    int j    = i & 7;
    int lane = (i >> 3) & 63;
    int nt   = (i >> 9) & 3;
    int q    = (i >> 11) & 1;
    int k    = i >> 12;
    int o = nt * 16 + (lane & 15);
    int c = q * 32 + ((lane >> 4) << 3) + j;
    wf[i] = (bf16_t)w[(o * CC + c) * KK + k];
}

__global__ __launch_bounds__(256, 4) void deform_conv_mfma(
    const float* __restrict__ x, const float* __restrict__ offset,
    const float* __restrict__ mask, const bf16x8* __restrict__ wf,
    const float* __restrict__ bias, float* __restrict__ out) {
    const int t    = threadIdx.x;
    // XCD-aware bijective swizzle: grid = 1024 = 8 * 128.
    const int wg   = (blockIdx.x & 7) * ((BB * 256) >> 3) + (blockIdx.x >> 3);
    const int b    = wg >> 8;
    const int ti   = wg & 255;                 // tile id: 16x16 tiles of 8x8
    const int r0   = ((ti >> 4) << 3);         // tile top row
    const int c0   = ((ti & 15) << 3);         // tile left col
    const int lane = t & 63;
    const int wv   = t >> 6;                   // wave: rows 2wv, 2wv+1
    const int col  = lane & 15;                // A-row m == pixel in wave
    const int quad = lane >> 4;
    const int prow = r0 + 2 * wv + (col >> 3); // this lane's pixel row
    const int pcol = c0 + (col & 7);
    const int rem  = prow * WW + pcol;
    const int wy0  = r0 - 4;                   // window origin (16x16 px)
    const int wx0  = c0 - 4;
    const int cb   = quad << 3;                // lane's 8-ch slot base

    __shared__ bf16_t V[256 * 64];             // 32 KB swizzled window

    const float* xb   = x + (size_t)b * CC * HW;
    const float* offp = offset + (size_t)b * (2 * KK) * HW + rem;
    const float* mp   = mask + (size_t)b * KK * HW + rem;

    // ---- stage 16x16-px window straight from NCHW fp32, clamped+swizzled ---
    // thread t: channel c = t>>2, px-quarter q = t&3. Clamped column
    // addresses and LDS element offsets are row-invariant.
    {
        const int c  = t >> 2;                 // 0..63
        const int q  = t & 3;
        const int ck = c >> 3;                 // 16B chunk index
        const int ce = c & 7;                  // element within chunk
        const float* xc = xb + (size_t)c * HW;
        const int jj0 = q * 4 + 0, jj1 = q * 4 + 1;
        const int jj2 = q * 4 + 2, jj3 = q * 4 + 3;
        const int cxa = min(max(wx0 + jj0, 0), WW - 1);
        const int cxb = min(max(wx0 + jj1, 0), WW - 1);
        const int cxc = min(max(wx0 + jj2, 0), WW - 1);
        const int cxd = min(max(wx0 + jj3, 0), WW - 1);
        const int e0 = jj0 * 64 + ((ck ^ (jj0 & 7)) << 3) + ce;
        const int e1 = jj1 * 64 + ((ck ^ (jj1 & 7)) << 3) + ce;
        const int e2 = jj2 * 64 + ((ck ^ (jj2 & 7)) << 3) + ce;
        const int e3 = jj3 * 64 + ((ck ^ (jj3 & 7)) << 3) + ce;
#pragma unroll
        for (int r = 0; r < 16; ++r) {
            const int cy = min(max(wy0 + r, 0), HH - 1);
            const float* row = xc + cy * WW;
            V[r * 1024 + e0] = (bf16_t)row[cxa];
            V[r * 1024 + e1] = (bf16_t)row[cxb];
            V[r * 1024 + e2] = (bf16_t)row[cxc];
            V[r * 1024 + e3] = (bf16_t)row[cxd];
        }
    }
    __syncthreads();

    f32x4 acc[4];
#pragma unroll
    for (int nt = 0; nt < 4; ++nt) acc[nt] = (f32x4){0.f, 0.f, 0.f, 0.f};

    float offy = offp[0];
    float offx = offp[HW];
    float mm   = mp[0];

#pragma unroll
    for (int k = 0; k < KK; ++k) {
        float n_offy = 0.f, n_offx = 0.f, n_mm = 0.f;
        if (k < KK - 1) {
            n_offy = offp[(2 * k + 2) * HW];
            n_offx = offp[(2 * k + 3) * HW];
            n_mm   = mp[(k + 1) * HW];
        }

        // ---- bilinear setup (exact reference semantics) ----
        float py = offy + (float)(k / KHW) + (float)(prow - 1);
        float px = offx + (float)(k % KHW) + (float)(pcol - 1);
        float fy0 = floorf(py), fx0 = floorf(px);
        float ly = py - fy0, lx = px - fx0;
        int y0 = (int)fy0, x0 = (int)fx0;
        int y1 = y0 + 1, x1 = x0 + 1;
        bool vy0 = (y0 >= 0) && (y0 < HH), vy1 = (y1 >= 0) && (y1 < HH);
        bool vx0 = (x0 >= 0) && (x0 < WW), vx1 = (x1 >= 0) && (x1 < WW);
        int cy0 = min(max(y0, 0), HH - 1), cy1 = min(max(y1, 0), HH - 1);
        int cx0 = min(max(x0, 0), WW - 1), cx1 = min(max(x1, 0), WW - 1);
        float w0 = (vy0 && vx0) ? mm * (1.0f - ly) * (1.0f - lx) : 0.0f;
        float w1 = (vy0 && vx1) ? mm * (1.0f - ly) * lx : 0.0f;
        float w2 = (vy1 && vx0) ? mm * ly * (1.0f - lx) : 0.0f;
        float w3 = (vy1 && vx1) ? mm * ly * lx : 0.0f;

        // ---- window-relative corner coords ----
        int uy0 = y0 - wy0, ux0 = x0 - wx0;
        int uy1 = uy0 + 1,  ux1 = ux0 + 1;
        bool iy0 = (unsigned)uy0 < 16u, iy1 = (unsigned)uy1 < 16u;
        bool ix0 = (unsigned)ux0 < 16u, ix1 = (unsigned)ux1 < 16u;
        int qy0 = min(max(uy0, 0), 15), qy1 = min(max(uy1, 0), 15);
        int qx0 = min(max(ux0, 0), 15), qx1 = min(max(ux1, 0), 15);
        int pa = (qy0 * 16 + qx0) * 64, pb = (qy0 * 16 + qx1) * 64;
        int pc = (qy1 * 16 + qx0) * 64, pd = (qy1 * 16 + qx1) * 64;
        int sa = (qx0 & 7), sb = (qx1 & 7);  // swizzle keys (row-indep)

        // ---- LDS gathers: g = chunk quad (ch cb..cb+7), h = chunk 4+quad ---
        bf16x8 g00 = *(const bf16x8*)&V[pa + ((quad ^ sa) << 3)];
        bf16x8 h00 = *(const bf16x8*)&V[pa + (((4 + quad) ^ sa) << 3)];
        bf16x8 g01 = *(const bf16x8*)&V[pb + ((quad ^ sb) << 3)];
        bf16x8 h01 = *(const bf16x8*)&V[pb + (((4 + quad) ^ sb) << 3)];
        bf16x8 g10 = *(const bf16x8*)&V[pc + ((quad ^ sa) << 3)];
        bf16x8 h10 = *(const bf16x8*)&V[pc + (((4 + quad) ^ sa) << 3)];
        bf16x8 g11 = *(const bf16x8*)&V[pd + ((quad ^ sb) << 3)];
        bf16x8 h11 = *(const bf16x8*)&V[pd + (((4 + quad) ^ sb) << 3)];

        // ---- rare out-of-window fallback (exec-masked, NCHW fp32 source) ---
        if (w0 != 0.0f && !(iy0 && ix0)) {
            const float* p = xb + (size_t)cb * HW + cy0 * WW + cx0;
#pragma unroll
            for (int i = 0; i < 8; ++i) {
                g00[i] = (bf16_t)p[i * HW];
                h00[i] = (bf16_t)p[(32 + i) * HW];
            }
        }
        if (w1 != 0.0f && !(iy0 && ix1)) {
            const float* p = xb + (size_t)cb * HW + cy0 * WW + cx1;
#pragma unroll
            for (int i = 0; i < 8; ++i) {
                g01[i] = (bf16_t)p[i * HW];
                h01[i] = (bf16_t)p[(32 + i) * HW];
            }
        }
        if (w2 != 0.0f && !(iy1 && ix0)) {
            const float* p = xb + (size_t)cb * HW + cy1 * WW + cx0;
#pragma unroll
            for (int i = 0; i < 8; ++i) {
                g10[i] = (bf16_t)p[i * HW];
                h10[i] = (bf16_t)p[(32 + i) * HW];
            }
        }
        if (w3 != 0.0f && !(iy1 && ix1)) {
            const float* p = xb + (size_t)cb * HW + cy1 * WW + cx1;
#pragma unroll
            for (int i = 0; i < 8; ++i) {
                g11[i] = (bf16_t)p[i * HW];
                h11[i] = (bf16_t)p[(32 + i) * HW];
            }
        }

        // ---- blend -> A fragments ----
        bf16x8 af0, af1;
#pragma unroll
        for (int i = 0; i < 8; ++i) {
            float v = w0 * (float)g00[i] + w1 * (float)g01[i] +
                      w2 * (float)g10[i] + w3 * (float)g11[i];
            af0[i] = (bf16_t)v;
        }
#pragma unroll
        for (int i = 0; i < 8; ++i) {
            float v = w0 * (float)h00[i] + w1 * (float)h01[i] +
                      w2 * (float)h10[i] + w3 * (float)h11[i];
            af1[i] = (bf16_t)v;
        }

        // ---- MFMA: 16 pixels x 64 outputs, K=64 (one tap) ----
#pragma unroll
        for (int nt = 0; nt < 4; ++nt) {
            bf16x8 bfg = wf[(k * 8 + nt) * 64 + lane];
            acc[nt] = __builtin_amdgcn_mfma_f32_16x16x32_bf16(
                af0, bfg, acc[nt], 0, 0, 0);
        }
#pragma unroll
        for (int nt = 0; nt < 4; ++nt) {
            bf16x8 bfg = wf[(k * 8 + 4 + nt) * 64 + lane];
            acc[nt] = __builtin_amdgcn_mfma_f32_16x16x32_bf16(
                af1, bfg, acc[nt], 0, 0, 0);
        }

        offy = n_offy;
        offx = n_offx;
        mm   = n_mm;
    }

    // ---- epilogue: D[row=quad*4+reg][col]; row -> pixel m, col -> output ---
    // m = quad*4+reg: out row r0+2wv+(quad>>1), cols c0+(quad&1)*4 .. +3.
#pragma unroll
    for (int nt = 0; nt < 4; ++nt) {
        int o = nt * 16 + col;
        float bv = bias[o];
        f32x4 r = acc[nt];
        r.x += bv; r.y += bv; r.z += bv; r.w += bv;
        float* dst = out + (size_t)(b * OO + o) * HW +
                     (r0 + 2 * wv + (quad >> 1)) * WW + c0 + (quad & 1) * 4;
        *(f32x4*)dst = r;  // 4 consecutive pixels, 16B aligned
    }
}

extern "C" void kernel_launch(void* const* d_in, const int* in_sizes, int n_in,
                              void* d_out, int out_size, void* d_ws,
                              size_t ws_size, hipStream_t stream) {
    const float* x      = (const float*)d_in[0];
    const float* offset = (const float*)d_in[1];
    const float* mask   = (const float*)d_in[2];
    const float* weight = (const float*)d_in[3];
    const float* bias   = (const float*)d_in[4];
    float* out = (float*)d_out;

    bf16_t* wfr = (bf16_t*)d_ws;                       // 72 KB

    int nw = OO * CC * KK;  // 36864
    wfrag_kernel<<<(nw + 255) / 256, 256, 0, stream>>>(weight, wfr);

    deform_conv_mfma<<<BB * (HW / 64), 256, 0, stream>>>(
        x, offset, mask, (const bf16x8*)wfr, bias, out);
}

// Round 8
// 103.421 us; speedup vs baseline: 1.1830x; 1.1830x over previous
//
#include <hip/hip_runtime.h>

// Modulated deformable conv2d, fp32 in/out, bf16 MFMA core.
// B=4, C=64, H=W=128, O=64, K=3x3, stride=1, pad=1, dil=1, og=1, groups=1.
//
// Round 13: revert r12's in-block staging (53 us: 128 scalar memops/thread)
// back to r11's proven split (total 100.1; main ~28 us under the 43 us
// 256MiB-workspace-fill floor). Deltas vs r11:
//  1. Prep store side vectorized: 2x bf16x8 packed stores per thread
//     (fully coalesced 1KB/wave) instead of 64 scalar 2B stores.
//  2. LDS swizzle key now (qx+qy)&7 on BOTH staging write and gather read
//     (row entropy -> fewer bank conflicts on random corners).
//  3. __launch_bounds__(256,5): 5 blocks/CU (LDS 32KB x 5 = 160KB exactly).
// Fragment layouts (m89/m120-verified): A[m=lane&15][k=quad*8+j],
// B[k=quad*8+j][n=lane&15], D[row=quad*4+reg][col=lane&15].

#define BB 4
#define CC 64
#define HH 128
#define WW 128
#define OO 64
#define KHW 3
#define KK 9
#define HW (HH * WW)

typedef __bf16 bf16_t;
typedef bf16_t bf16x8 __attribute__((ext_vector_type(8)));
typedef float f32x4 __attribute__((ext_vector_type(4)));

// ---- prep: x (NCHW fp32) -> xt (NHWC bf16)  +  weight -> B-fragment bf16 ----
// blocks [0, BB*256): transpose; blocks [BB*256, +144): weight repack.
__global__ __launch_bounds__(256) void prep_kernel(const float* __restrict__ x,
                                                   bf16_t* __restrict__ xt,
                                                   const float* __restrict__ w,
                                                   bf16_t* __restrict__ wf) {
    __shared__ float tile[64 * 65];
    const int t = threadIdx.x;
    if (blockIdx.x < BB * 256) {
        const int b  = blockIdx.x >> 8;
        const int p0 = (blockIdx.x & 255) << 6;
#pragma unroll
        for (int i = 0; i < 16; ++i) {
            int c = i * 4 + (t >> 6);
            int p = t & 63;
            tile[c * 65 + p] = x[(b * CC + c) * HW + p0 + p];  // coalesced
        }
        __syncthreads();
        // store: thread t -> pixel p = t>>2, chunks q and q+4 (q = t&3).
        // Lanes 4i..4i+3 emit px i's full 128B -> 1KB coalesced per wave.
        const int p = t >> 2;
        const int q = t & 3;
        bf16x8 v0, v1;
#pragma unroll
        for (int e = 0; e < 8; ++e) v0[e] = (bf16_t)tile[(q * 8 + e) * 65 + p];
#pragma unroll
        for (int e = 0; e < 8; ++e)
            v1[e] = (bf16_t)tile[((q + 4) * 8 + e) * 65 + p];
        bf16_t* dst = xt + (size_t)((b * HW) + p0 + p) * CC;
        *(bf16x8*)(dst + q * 8) = v0;
        *(bf16x8*)(dst + (q + 4) * 8) = v1;
    } else {
        // wf element index: ((tap*2+q)*4+nt)*64*8 + lane*8 + j
        //   holds W[o = nt*16 + (lane&15)][c = q*32 + (lane>>4)*8 + j][tap]
        int i = (blockIdx.x - BB * 256) * 256 + t;
        if (i >= OO * CC * KK) return;
        int j    = i & 7;
        int lane = (i >> 3) & 63;
        int nt   = (i >> 9) & 3;
        int q    = (i >> 11) & 1;
        int k    = i >> 12;
        int o = nt * 16 + (lane & 15);
        int c = q * 32 + ((lane >> 4) << 3) + j;
        wf[i] = (bf16_t)w[(o * CC + c) * KK + k];
    }
}

__global__ __launch_bounds__(256, 5) void deform_conv_mfma(
    const bf16_t* __restrict__ xt, const float* __restrict__ offset,
    const float* __restrict__ mask, const bf16x8* __restrict__ wf,
    const float* __restrict__ bias, float* __restrict__ out) {
    const int t    = threadIdx.x;
    // XCD-aware bijective swizzle: grid = 1024 = 8 * 128.
    const int wg   = (blockIdx.x & 7) * ((BB * 256) >> 3) + (blockIdx.x >> 3);
    const int b    = wg >> 8;
    const int ti   = wg & 255;                 // tile id: 16x16 tiles of 8x8
    const int r0   = ((ti >> 4) << 3);         // tile top row
    const int c0   = ((ti & 15) << 3);         // tile left col
    const int lane = t & 63;
    const int wv   = t >> 6;                   // wave: rows 2wv, 2wv+1
    const int col  = lane & 15;                // A-row m == pixel in wave
    const int quad = lane >> 4;
    const int prow = r0 + 2 * wv + (col >> 3); // this lane's pixel row
    const int pcol = c0 + (col & 7);
    const int rem  = prow * WW + pcol;
    const int wy0  = r0 - 4;                   // window origin (16x16 px)
    const int wx0  = c0 - 4;
    const int cb   = quad << 3;                // lane's 8-ch slot base

    __shared__ bf16_t V[256 * 64];             // 32 KB swizzled window

    const bf16_t* xb  = xt + (size_t)b * HW * CC;
    const float* offp = offset + (size_t)b * (2 * KK) * HW + rem;
    const float* mp   = mask + (size_t)b * KK * HW + rem;

    // ---- stage 16x16-pixel window, clamped, chunk-swizzled (key (i+j)&7) ---
    {
        const int i  = t >> 4;                 // window row 0..15
        const int j  = t & 15;                 // window col 0..15
        const int cy = min(max(wy0 + i, 0), HH - 1);
        const int cx = min(max(wx0 + j, 0), WW - 1);
        const bf16_t* src = xb + (size_t)(cy * WW + cx) * CC;
        bf16_t* dst = &V[(i * 16 + j) * 64];
        const int sw = ((i + j) & 7) * 8;
#pragma unroll
        for (int s = 0; s < 8; ++s)
            *(bf16x8*)(dst + ((s * 8) ^ sw)) = *(const bf16x8*)(src + s * 8);
    }
    __syncthreads();

    f32x4 acc[4];
#pragma unroll
    for (int nt = 0; nt < 4; ++nt) acc[nt] = (f32x4){0.f, 0.f, 0.f, 0.f};

    float offy = offp[0];
    float offx = offp[HW];
    float mm   = mp[0];

#pragma unroll
    for (int k = 0; k < KK; ++k) {
        float n_offy = 0.f, n_offx = 0.f, n_mm = 0.f;
        if (k < KK - 1) {
            n_offy = offp[(2 * k + 2) * HW];
            n_offx = offp[(2 * k + 3) * HW];
            n_mm   = mp[(k + 1) * HW];
        }

        // ---- bilinear setup (exact reference semantics) ----
        float py = offy + (float)(k / KHW) + (float)(prow - 1);
        float px = offx + (float)(k % KHW) + (float)(pcol - 1);
        float fy0 = floorf(py), fx0 = floorf(px);
        float ly = py - fy0, lx = px - fx0;
        int y0 = (int)fy0, x0 = (int)fx0;
        int y1 = y0 + 1, x1 = x0 + 1;
        bool vy0 = (y0 >= 0) && (y0 < HH), vy1 = (y1 >= 0) && (y1 < HH);
        bool vx0 = (x0 >= 0) && (x0 < WW), vx1 = (x1 >= 0) && (x1 < WW);
        int cy0 = min(max(y0, 0), HH - 1), cy1 = min(max(y1, 0), HH - 1);
        int cx0 = min(max(x0, 0), WW - 1), cx1 = min(max(x1, 0), WW - 1);
        float w0 = (vy0 && vx0) ? mm * (1.0f - ly) * (1.0f - lx) : 0.0f;
        float w1 = (vy0 && vx1) ? mm * (1.0f - ly) * lx : 0.0f;
        float w2 = (vy1 && vx0) ? mm * ly * (1.0f - lx) : 0.0f;
        float w3 = (vy1 && vx1) ? mm * ly * lx : 0.0f;

        // ---- window-relative corner coords ----
        int uy0 = y0 - wy0, ux0 = x0 - wx0;
        int uy1 = uy0 + 1,  ux1 = ux0 + 1;
        bool iy0 = (unsigned)uy0 < 16u, iy1 = (unsigned)uy1 < 16u;
        bool ix0 = (unsigned)ux0 < 16u, ix1 = (unsigned)ux1 < 16u;
        int qy0 = min(max(uy0, 0), 15), qy1 = min(max(uy1, 0), 15);
        int qx0 = min(max(ux0, 0), 15), qx1 = min(max(ux1, 0), 15);
        int pa = (qy0 * 16 + qx0) * 64, pb = (qy0 * 16 + qx1) * 64;
        int pc = (qy1 * 16 + qx0) * 64, pd = (qy1 * 16 + qx1) * 64;
        int k00 = (qx0 + qy0) & 7, k01 = (qx1 + qy0) & 7;  // swizzle keys
        int k10 = (qx0 + qy1) & 7, k11 = (qx1 + qy1) & 7;

        // ---- LDS gathers: g = chunk quad (ch cb..cb+7), h = chunk 4+quad ---
        bf16x8 g00 = *(const bf16x8*)&V[pa + ((quad ^ k00) << 3)];
        bf16x8 h00 = *(const bf16x8*)&V[pa + (((4 + quad) ^ k00) << 3)];
        bf16x8 g01 = *(const bf16x8*)&V[pb + ((quad ^ k01) << 3)];
        bf16x8 h01 = *(const bf16x8*)&V[pb + (((4 + quad) ^ k01) << 3)];
        bf16x8 g10 = *(const bf16x8*)&V[pc + ((quad ^ k10) << 3)];
        bf16x8 h10 = *(const bf16x8*)&V[pc + (((4 + quad) ^ k10) << 3)];
        bf16x8 g11 = *(const bf16x8*)&V[pd + ((quad ^ k11) << 3)];
        bf16x8 h11 = *(const bf16x8*)&V[pd + (((4 + quad) ^ k11) << 3)];

        // ---- rare out-of-window fallback (exec-masked, usually skipped) ----
        if (w0 != 0.0f && !(iy0 && ix0)) {
            const bf16_t* p = xb + (size_t)(cy0 * WW + cx0) * CC + cb;
            g00 = *(const bf16x8*)p; h00 = *(const bf16x8*)(p + 32);
        }
        if (w1 != 0.0f && !(iy0 && ix1)) {
            const bf16_t* p = xb + (size_t)(cy0 * WW + cx1) * CC + cb;
            g01 = *(const bf16x8*)p; h01 = *(const bf16x8*)(p + 32);
        }
        if (w2 != 0.0f && !(iy1 && ix0)) {
            const bf16_t* p = xb + (size_t)(cy1 * WW + cx0) * CC + cb;
            g10 = *(const bf16x8*)p; h10 = *(const bf16x8*)(p + 32);
        }
        if (w3 != 0.0f && !(iy1 && ix1)) {
            const bf16_t* p = xb + (size_t)(cy1 * WW + cx1) * CC + cb;
            g11 = *(const bf16x8*)p; h11 = *(const bf16x8*)(p + 32);
        }

        // ---- blend -> A fragments ----
        bf16x8 af0, af1;
#pragma unroll
        for (int i = 0; i < 8; ++i) {
            float v = w0 * (float)g00[i] + w1 * (float)g01[i] +
                      w2 * (float)g10[i] + w3 * (float)g11[i];
            af0[i] = (bf16_t)v;
        }
#pragma unroll
        for (int i = 0; i < 8; ++i) {
            float v = w0 * (float)h00[i] + w1 * (float)h01[i] +
                      w2 * (float)h10[i] + w3 * (float)h11[i];
            af1[i] = (bf16_t)v;
        }

        // ---- MFMA: 16 pixels x 64 outputs, K=64 (one tap) ----
#pragma unroll
        for (int nt = 0; nt < 4; ++nt) {
            bf16x8 bfg = wf[(k * 8 + nt) * 64 + lane];
            acc[nt] = __builtin_amdgcn_mfma_f32_16x16x32_bf16(
                af0, bfg, acc[nt], 0, 0, 0);
        }
#pragma unroll
        for (int nt = 0; nt < 4; ++nt) {
            bf16x8 bfg = wf[(k * 8 + 4 + nt) * 64 + lane];
            acc[nt] = __builtin_amdgcn_mfma_f32_16x16x32_bf16(
                af1, bfg, acc[nt], 0, 0, 0);
        }

        offy = n_offy;
        offx = n_offx;
        mm   = n_mm;
    }

    // ---- epilogue: D[row=quad*4+reg][col]; row -> pixel m, col -> output ---
    // m = quad*4+reg: out row r0+2wv+(quad>>1), cols c0+(quad&1)*4 .. +3.
#pragma unroll
    for (int nt = 0; nt < 4; ++nt) {
        int o = nt * 16 + col;
        float bv = bias[o];
        f32x4 r = acc[nt];
        r.x += bv; r.y += bv; r.z += bv; r.w += bv;
        float* dst = out + (size_t)(b * OO + o) * HW +
                     (r0 + 2 * wv + (quad >> 1)) * WW + c0 + (quad & 1) * 4;
        *(f32x4*)dst = r;  // 4 consecutive pixels, 16B aligned
    }
}

extern "C" void kernel_launch(void* const* d_in, const int* in_sizes, int n_in,
                              void* d_out, int out_size, void* d_ws,
                              size_t ws_size, hipStream_t stream) {
    const float* x      = (const float*)d_in[0];
    const float* offset = (const float*)d_in[1];
    const float* mask   = (const float*)d_in[2];
    const float* weight = (const float*)d_in[3];
    const float* bias   = (const float*)d_in[4];
    float* out = (float*)d_out;

    bf16_t* xt  = (bf16_t*)d_ws;                       // 4*16384*64*2 = 8 MB
    bf16_t* wfr = (bf16_t*)((char*)d_ws + (size_t)BB * HW * CC * 2);  // 72 KB

    int nwf_blocks = (OO * CC * KK + 255) / 256;       // 144
    prep_kernel<<<BB * 256 + nwf_blocks, 256, 0, stream>>>(x, xt, weight, wfr);

    deform_conv_mfma<<<BB * (HW / 64), 256, 0, stream>>>(
        xt, offset, mask, (const bf16x8*)wfr, bias, out);
}

// Round 10
// 102.278 us; speedup vs baseline: 1.1962x; 1.0112x over previous
//
#include <hip/hip_runtime.h>

// Modulated deformable conv2d, fp32 in/out, bf16 MFMA core.
// B=4, C=64, H=W=128, O=64, K=3x3, stride=1, pad=1, dil=1, og=1, groups=1.
//
// Round 15: r14's cooperative launch never ran (absmax 2.4 == max|ref| ->
// output stayed memset-zero; hipLaunchCooperativeKernel is not graph-
// capturable in this harness). Revert to the proven two-launch structure.
// This round = r11 EXACTLY (best passing total, 100.1 us) + the one
// r13 delta that is outside the hot loop and correctness-proven:
// vectorized prep store (2x bf16x8 coalesced stores vs 64 scalar 2B).
// Main kernel untouched from r11: qx&7 swizzle keys, launch_bounds(256,4).
// Fragment layouts (m89/m120-verified): A[m=lane&15][k=quad*8+j],
// B[k=quad*8+j][n=lane&15], D[row=quad*4+reg][col=lane&15].

#define BB 4
#define CC 64
#define HH 128
#define WW 128
#define OO 64
#define KHW 3
#define KK 9
#define HW (HH * WW)

typedef __bf16 bf16_t;
typedef bf16_t bf16x8 __attribute__((ext_vector_type(8)));
typedef float f32x4 __attribute__((ext_vector_type(4)));

// ---- prep: x (NCHW fp32) -> xt (NHWC bf16)  +  weight -> B-fragment bf16 ----
// blocks [0, BB*256): transpose; blocks [BB*256, +144): weight repack.
__global__ __launch_bounds__(256) void prep_kernel(const float* __restrict__ x,
                                                   bf16_t* __restrict__ xt,
                                                   const float* __restrict__ w,
                                                   bf16_t* __restrict__ wf) {
    __shared__ float tile[64 * 65];
    const int t = threadIdx.x;
    if (blockIdx.x < BB * 256) {
        const int b  = blockIdx.x >> 8;
        const int p0 = (blockIdx.x & 255) << 6;
#pragma unroll
        for (int i = 0; i < 16; ++i) {
            int c = i * 4 + (t >> 6);
            int p = t & 63;
            tile[c * 65 + p] = x[(b * CC + c) * HW + p0 + p];  // coalesced
        }
        __syncthreads();
        // store: thread t -> pixel p = t>>2, chunks q and q+4 (q = t&3).
        // Lanes 4i..4i+3 emit px i's full 128B -> 1KB coalesced per wave.
        const int p = t >> 2;
        const int q = t & 3;
        bf16x8 v0, v1;
#pragma unroll
        for (int e = 0; e < 8; ++e) v0[e] = (bf16_t)tile[(q * 8 + e) * 65 + p];
#pragma unroll
        for (int e = 0; e < 8; ++e)
            v1[e] = (bf16_t)tile[((q + 4) * 8 + e) * 65 + p];
        bf16_t* dst = xt + (size_t)((b * HW) + p0 + p) * CC;
        *(bf16x8*)(dst + q * 8) = v0;
        *(bf16x8*)(dst + (q + 4) * 8) = v1;
    } else {
        // wf element index: ((tap*2+q)*4+nt)*64*8 + lane*8 + j
        //   holds W[o = nt*16 + (lane&15)][c = q*32 + (lane>>4)*8 + j][tap]
        int i = (blockIdx.x - BB * 256) * 256 + t;
        if (i >= OO * CC * KK) return;
        int j    = i & 7;
        int lane = (i >> 3) & 63;
        int nt   = (i >> 9) & 3;
        int q    = (i >> 11) & 1;
        int k    = i >> 12;
        int o = nt * 16 + (lane & 15);
        int c = q * 32 + ((lane >> 4) << 3) + j;
        wf[i] = (bf16_t)w[(o * CC + c) * KK + k];
    }
}

__global__ __launch_bounds__(256, 4) void deform_conv_mfma(
    const bf16_t* __restrict__ xt, const float* __restrict__ offset,
    const float* __restrict__ mask, const bf16x8* __restrict__ wf,
    const float* __restrict__ bias, float* __restrict__ out) {
    const int t    = threadIdx.x;
    // XCD-aware bijective swizzle: grid = 1024 = 8 * 128.
    const int wg   = (blockIdx.x & 7) * ((BB * 256) >> 3) + (blockIdx.x >> 3);
    const int b    = wg >> 8;
    const int ti   = wg & 255;                 // tile id: 16x16 tiles of 8x8
    const int r0   = ((ti >> 4) << 3);         // tile top row
    const int c0   = ((ti & 15) << 3);         // tile left col
    const int lane = t & 63;
    const int wv   = t >> 6;                   // wave: rows 2wv, 2wv+1
    const int col  = lane & 15;                // A-row m == pixel in wave
    const int quad = lane >> 4;
    const int prow = r0 + 2 * wv + (col >> 3); // this lane's pixel row
    const int pcol = c0 + (col & 7);
    const int rem  = prow * WW + pcol;
    const int wy0  = r0 - 4;                   // window origin (16x16 px)
    const int wx0  = c0 - 4;
    const int cb   = quad << 3;                // lane's 8-ch slot base

    __shared__ bf16_t V[256 * 64];             // 32 KB swizzled window

    const bf16_t* xb  = xt + (size_t)b * HW * CC;
    const float* offp = offset + (size_t)b * (2 * KK) * HW + rem;
    const float* mp   = mask + (size_t)b * KK * HW + rem;

    // ---- stage 16x16-pixel window, clamped, chunk-swizzled ----
    {
        const int i  = t >> 4;                 // window row 0..15
        const int j  = t & 15;                 // window col 0..15
        const int cy = min(max(wy0 + i, 0), HH - 1);
        const int cx = min(max(wx0 + j, 0), WW - 1);
        const bf16_t* src = xb + (size_t)(cy * WW + cx) * CC;
        bf16_t* dst = &V[(i * 16 + j) * 64];
        const int sw = (j & 7) * 8;
#pragma unroll
        for (int s = 0; s < 8; ++s)
            *(bf16x8*)(dst + ((s * 8) ^ sw)) = *(const bf16x8*)(src + s * 8);
    }
    __syncthreads();

    f32x4 acc[4];
#pragma unroll
    for (int nt = 0; nt < 4; ++nt) acc[nt] = (f32x4){0.f, 0.f, 0.f, 0.f};

    float offy = offp[0];
    float offx = offp[HW];
    float mm   = mp[0];

#pragma unroll
    for (int k = 0; k < KK; ++k) {
        float n_offy = 0.f, n_offx = 0.f, n_mm = 0.f;
        if (k < KK - 1) {
            n_offy = offp[(2 * k + 2) * HW];
            n_offx = offp[(2 * k + 3) * HW];
            n_mm   = mp[(k + 1) * HW];
        }

        // ---- bilinear setup (exact reference semantics) ----
        float py = offy + (float)(k / KHW) + (float)(prow - 1);
        float px = offx + (float)(k % KHW) + (float)(pcol - 1);
        float fy0 = floorf(py), fx0 = floorf(px);
        float ly = py - fy0, lx = px - fx0;
        int y0 = (int)fy0, x0 = (int)fx0;
        int y1 = y0 + 1, x1 = x0 + 1;
        bool vy0 = (y0 >= 0) && (y0 < HH), vy1 = (y1 >= 0) && (y1 < HH);
        bool vx0 = (x0 >= 0) && (x0 < WW), vx1 = (x1 >= 0) && (x1 < WW);
        int cy0 = min(max(y0, 0), HH - 1), cy1 = min(max(y1, 0), HH - 1);
        int cx0 = min(max(x0, 0), WW - 1), cx1 = min(max(x1, 0), WW - 1);
        float w0 = (vy0 && vx0) ? mm * (1.0f - ly) * (1.0f - lx) : 0.0f;
        float w1 = (vy0 && vx1) ? mm * (1.0f - ly) * lx : 0.0f;
        float w2 = (vy1 && vx0) ? mm * ly * (1.0f - lx) : 0.0f;
        float w3 = (vy1 && vx1) ? mm * ly * lx : 0.0f;

        // ---- window-relative corner coords ----
        int uy0 = y0 - wy0, ux0 = x0 - wx0;
        int uy1 = uy0 + 1,  ux1 = ux0 + 1;
        bool iy0 = (unsigned)uy0 < 16u, iy1 = (unsigned)uy1 < 16u;
        bool ix0 = (unsigned)ux0 < 16u, ix1 = (unsigned)ux1 < 16u;
        int qy0 = min(max(uy0, 0), 15), qy1 = min(max(uy1, 0), 15);
        int qx0 = min(max(ux0, 0), 15), qx1 = min(max(ux1, 0), 15);
        int pa = (qy0 * 16 + qx0) * 64, pb = (qy0 * 16 + qx1) * 64;
        int pc = (qy1 * 16 + qx0) * 64, pd = (qy1 * 16 + qx1) * 64;
        int sa = (qx0 & 7), sb = (qx1 & 7);  // swizzle keys (row-indep)

        // ---- LDS gathers: g = chunk quad (ch cb..cb+7), h = chunk 4+quad ---
        bf16x8 g00 = *(const bf16x8*)&V[pa + ((quad ^ sa) << 3)];
        bf16x8 h00 = *(const bf16x8*)&V[pa + (((4 + quad) ^ sa) << 3)];
        bf16x8 g01 = *(const bf16x8*)&V[pb + ((quad ^ sb) << 3)];
        bf16x8 h01 = *(const bf16x8*)&V[pb + (((4 + quad) ^ sb) << 3)];
        bf16x8 g10 = *(const bf16x8*)&V[pc + ((quad ^ sa) << 3)];
        bf16x8 h10 = *(const bf16x8*)&V[pc + (((4 + quad) ^ sa) << 3)];
        bf16x8 g11 = *(const bf16x8*)&V[pd + ((quad ^ sb) << 3)];
        bf16x8 h11 = *(const bf16x8*)&V[pd + (((4 + quad) ^ sb) << 3)];

        // ---- rare out-of-window fallback (exec-masked, usually skipped) ----
        if (w0 != 0.0f && !(iy0 && ix0)) {
            const bf16_t* p = xb + (size_t)(cy0 * WW + cx0) * CC + cb;
            g00 = *(const bf16x8*)p; h00 = *(const bf16x8*)(p + 32);
        }
        if (w1 != 0.0f && !(iy0 && ix1)) {
            const bf16_t* p = xb + (size_t)(cy0 * WW + cx1) * CC + cb;
            g01 = *(const bf16x8*)p; h01 = *(const bf16x8*)(p + 32);
        }
        if (w2 != 0.0f && !(iy1 && ix0)) {
            const bf16_t* p = xb + (size_t)(cy1 * WW + cx0) * CC + cb;
            g10 = *(const bf16x8*)p; h10 = *(const bf16x8*)(p + 32);
        }
        if (w3 != 0.0f && !(iy1 && ix1)) {
            const bf16_t* p = xb + (size_t)(cy1 * WW + cx1) * CC + cb;
            g11 = *(const bf16x8*)p; h11 = *(const bf16x8*)(p + 32);
        }

        // ---- blend -> A fragments ----
        bf16x8 af0, af1;
#pragma unroll
        for (int i = 0; i < 8; ++i) {
            float v = w0 * (float)g00[i] + w1 * (float)g01[i] +
                      w2 * (float)g10[i] + w3 * (float)g11[i];
            af0[i] = (bf16_t)v;
        }
#pragma unroll
        for (int i = 0; i < 8; ++i) {
            float v = w0 * (float)h00[i] + w1 * (float)h01[i] +
                      w2 * (float)h10[i] + w3 * (float)h11[i];
            af1[i] = (bf16_t)v;
        }

        // ---- MFMA: 16 pixels x 64 outputs, K=64 (one tap) ----
#pragma unroll
        for (int nt = 0; nt < 4; ++nt) {
            bf16x8 bfg = wf[(k * 8 + nt) * 64 + lane];
            acc[nt] = __builtin_amdgcn_mfma_f32_16x16x32_bf16(
                af0, bfg, acc[nt], 0, 0, 0);
        }
#pragma unroll
        for (int nt = 0; nt < 4; ++nt) {
            bf16x8 bfg = wf[(k * 8 + 4 + nt) * 64 + lane];
            acc[nt] = __builtin_amdgcn_mfma_f32_16x16x32_bf16(
                af1, bfg, acc[nt], 0, 0, 0);
        }

        offy = n_offy;
        offx = n_offx;
        mm   = n_mm;
    }

    // ---- epilogue: D[row=quad*4+reg][col]; row -> pixel m, col -> output ---
    // m = quad*4+reg: out row r0+2wv+(quad>>1), cols c0+(quad&1)*4 .. +3.
#pragma unroll
    for (int nt = 0; nt < 4; ++nt) {
        int o = nt * 16 + col;
        float bv = bias[o];
        f32x4 r = acc[nt];
        r.x += bv; r.y += bv; r.z += bv; r.w += bv;
        float* dst = out + (size_t)(b * OO + o) * HW +
                     (r0 + 2 * wv + (quad >> 1)) * WW + c0 + (quad & 1) * 4;
        *(f32x4*)dst = r;  // 4 consecutive pixels, 16B aligned
    }
}

extern "C" void kernel_launch(void* const* d_in, const int* in_sizes, int n_in,
                              void* d_out, int out_size, void* d_ws,
                              size_t ws_size, hipStream_t stream) {
    const float* x      = (const float*)d_in[0];
    const float* offset = (const float*)d_in[1];
    const float* mask   = (const float*)d_in[2];
    const float* weight = (const float*)d_in[3];
    const float* bias   = (const float*)d_in[4];
    float* out = (float*)d_out;

    bf16_t* xt  = (bf16_t*)d_ws;                       // 4*16384*64*2 = 8 MB
    bf16_t* wfr = (bf16_t*)((char*)d_ws + (size_t)BB * HW * CC * 2);  // 72 KB

    int nwf_blocks = (OO * CC * KK + 255) / 256;       // 144
    prep_kernel<<<BB * 256 + nwf_blocks, 256, 0, stream>>>(x, xt, weight, wfr);

    deform_conv_mfma<<<BB * (HW / 64), 256, 0, stream>>>(
        xt, offset, mask, (const bf16x8*)wfr, bias, out);
}